// Round 1
// baseline (37.422 us; speedup 1.0000x reference)
//
#include <hip/hip_runtime.h>
#include <math.h>

#define NBATCH 2
#define NSEQ   1024
#define DDIM   256
#define LUT_N  4096   // intervals; LUT_N+1 entries over corr in [-1, 1]

__device__ __forceinline__ float wave_reduce_sum(float v) {
#pragma unroll
  for (int off = 32; off > 0; off >>= 1)
    v += __shfl_xor(v, off, 64);
  return v;
}

// One wave per row: center along feature dim, compute un-normalized std norm.
__global__ __launch_bounds__(256) void prep_kernel(
    const float* __restrict__ fin, const float* __restrict__ sin_,
    float* __restrict__ fc, float* __restrict__ sc,
    float* __restrict__ fn, float* __restrict__ sn) {
  const int lane = threadIdx.x & 63;
  const int row  = blockIdx.x * 4 + (threadIdx.x >> 6);  // 0..2047 (B*N)
  const float* src = blockIdx.y ? sin_ : fin;
  float* dc = blockIdx.y ? sc : fc;
  float* dn = blockIdx.y ? sn : fn;

  const float4 v = *reinterpret_cast<const float4*>(&src[(size_t)row * DDIM + lane * 4]);
  const float mean = wave_reduce_sum(v.x + v.y + v.z + v.w) * (1.0f / DDIM);
  const float4 c = make_float4(v.x - mean, v.y - mean, v.z - mean, v.w - mean);
  const float sq = wave_reduce_sum(c.x * c.x + c.y * c.y + c.z * c.z + c.w * c.w);
  *reinterpret_cast<float4*>(&dc[(size_t)row * DDIM + lane * 4]) = c;
  if (lane == 0) dn[row] = fmaxf(sqrtf(sq), 1e-6f);
}

// LUT over corr in [-1,1]: lut[e] = sum_h gelu(exp(c)*w1[h]+b1[h])*w2[h] + b2.
// One wave per entry; 2 hidden units per lane.
__global__ __launch_bounds__(256) void lut_kernel(
    const float* __restrict__ w1, const float* __restrict__ b1,
    const float* __restrict__ w2, const float* __restrict__ b2,
    float* __restrict__ lut) {
  const int lane = threadIdx.x & 63;
  const int e = blockIdx.x * 4 + (threadIdx.x >> 6);
  if (e > LUT_N) return;
  const float corr = -1.0f + (float)e * (2.0f / LUT_N);
  const float a = expf(corr);
  float acc = 0.0f;
#pragma unroll
  for (int h = lane; h < 128; h += 64) {
    const float x = fmaf(a, w1[h], b1[h]);
    const float g = 0.5f * x * (1.0f + erff(x * 0.70710678118654752f));
    acc = fmaf(g, w2[h], acc);
  }
  acc = wave_reduce_sum(acc);
  if (lane == 0) lut[e] = acc + b2[0];
}

// 64x64 output tile per block, 16x16 threads, 4x4 per thread, BK=32.
// k-major LDS tiles (stride 68): inner reads are broadcast / 2-way max.
__global__ __launch_bounds__(256) void gemm_lut_kernel(
    const float* __restrict__ fc, const float* __restrict__ sc,
    const float* __restrict__ fn, const float* __restrict__ sn,
    const float* __restrict__ lut, float* __restrict__ out) {
  __shared__ float As[32][68];
  __shared__ float Bs[32][68];
  __shared__ float lut_s[LUT_N + 2];

  const int t  = threadIdx.x;
  const int tx = t & 15;   // col group (n/m dim of structural)
  const int ty = t >> 4;   // row group (functional)
  const int bz = blockIdx.z;
  const int brow = blockIdx.y * 64;
  const int bcol = blockIdx.x * 64;

  for (int i = t; i <= LUT_N; i += 256) lut_s[i] = lut[i];

  const float* Ag = fc + ((size_t)bz * NSEQ + brow) * DDIM;
  const float* Bg = sc + ((size_t)bz * NSEQ + bcol) * DDIM;

  const int kq = (t & 7) << 2;  // 0,4,...,28 within BK
  const int m0 = t >> 3;        // 0..31

  float acc[4][4] = {{0.0f}};

  for (int kt = 0; kt < DDIM; kt += 32) {
    if (kt) __syncthreads();
#pragma unroll
    for (int half = 0; half < 2; ++half) {
      const int m = m0 + half * 32;
      const float4 a = *reinterpret_cast<const float4*>(&Ag[(size_t)m * DDIM + kt + kq]);
      As[kq + 0][m] = a.x; As[kq + 1][m] = a.y; As[kq + 2][m] = a.z; As[kq + 3][m] = a.w;
      const float4 b = *reinterpret_cast<const float4*>(&Bg[(size_t)m * DDIM + kt + kq]);
      Bs[kq + 0][m] = b.x; Bs[kq + 1][m] = b.y; Bs[kq + 2][m] = b.z; Bs[kq + 3][m] = b.w;
    }
    __syncthreads();
#pragma unroll
    for (int k = 0; k < 32; ++k) {
      const float4 av = *reinterpret_cast<const float4*>(&As[k][ty * 4]);
      const float4 bv = *reinterpret_cast<const float4*>(&Bs[k][tx * 4]);
      const float aa[4] = {av.x, av.y, av.z, av.w};
      const float bb[4] = {bv.x, bv.y, bv.z, bv.w};
#pragma unroll
      for (int i = 0; i < 4; ++i)
#pragma unroll
        for (int j = 0; j < 4; ++j)
          acc[i][j] = fmaf(aa[i], bb[j], acc[i][j]);
    }
  }

  // Epilogue: corr -> LUT interp -> out
  float fs[4], ss[4];
#pragma unroll
  for (int i = 0; i < 4; ++i) fs[i] = fn[bz * NSEQ + brow + ty * 4 + i];
#pragma unroll
  for (int j = 0; j < 4; ++j) ss[j] = sn[bz * NSEQ + bcol + tx * 4 + j];

#pragma unroll
  for (int i = 0; i < 4; ++i) {
    float4 o;
    float* op = reinterpret_cast<float*>(&o);
#pragma unroll
    for (int j = 0; j < 4; ++j) {
      const float cov  = acc[i][j] * (1.0f / 16.0f);  // / sqrt(256)
      const float den  = fmaxf(fs[i] * ss[j], 1e-6f);
      const float corr = fminf(fmaxf(cov / den, -1.0f), 1.0f);
      const float tf = (corr + 1.0f) * (float)(LUT_N / 2);
      int idx = (int)tf;
      idx = idx > (LUT_N - 1) ? (LUT_N - 1) : idx;
      const float fr = tf - (float)idx;
      op[j] = fmaf(fr, lut_s[idx + 1] - lut_s[idx], lut_s[idx]);
    }
    const size_t orow = ((size_t)bz * NSEQ + brow + ty * 4 + i) * NSEQ + bcol + tx * 4;
    *reinterpret_cast<float4*>(&out[orow]) = o;
  }
}

extern "C" void kernel_launch(void* const* d_in, const int* in_sizes, int n_in,
                              void* d_out, int out_size, void* d_ws, size_t ws_size,
                              hipStream_t stream) {
  const float* f  = (const float*)d_in[0];
  const float* s  = (const float*)d_in[1];
  const float* w1 = (const float*)d_in[2];
  const float* b1 = (const float*)d_in[3];
  const float* w2 = (const float*)d_in[4];
  const float* b2 = (const float*)d_in[5];
  float* out = (float*)d_out;

  float* fc  = (float*)d_ws;
  float* sc  = fc + (size_t)NBATCH * NSEQ * DDIM;
  float* fn  = sc + (size_t)NBATCH * NSEQ * DDIM;
  float* sn  = fn + (size_t)NBATCH * NSEQ;
  float* lut = sn + (size_t)NBATCH * NSEQ;

  prep_kernel<<<dim3(512, 2), 256, 0, stream>>>(f, s, fc, sc, fn, sn);
  lut_kernel<<<(LUT_N + 1 + 3) / 4, 256, 0, stream>>>(w1, b1, w2, b2, lut);
  gemm_lut_kernel<<<dim3(16, 16, 2), 256, 0, stream>>>(fc, sc, fn, sn, lut, out);
}

// Round 2
// 23.298 us; speedup vs baseline: 1.6062x; 1.6062x over previous
//
#include <hip/hip_runtime.h>
#include <math.h>

#define NB   2
#define NSEQ 1024
#define DD   256
#define LUTN 4096   // intervals; LUTN+1 entries over corr in [-1,1]

#define BM 128
#define BN 64
#define BK 64

typedef _Float16 f16;
typedef _Float16 f16x4 __attribute__((ext_vector_type(4)));
typedef _Float16 f16x8 __attribute__((ext_vector_type(8)));
typedef float f32x4 __attribute__((ext_vector_type(4)));

__device__ __forceinline__ float wrsum(float v) {
#pragma unroll
  for (int off = 32; off > 0; off >>= 1) v += __shfl_xor(v, off, 64);
  return v;
}

// One wave per row: center (fp32), split to f16 hi+lo, write reciprocal norm.
__global__ __launch_bounds__(256) void prep_kernel(
    const float* __restrict__ fin, const float* __restrict__ sin_,
    f16* __restrict__ fh, f16* __restrict__ fl,
    f16* __restrict__ sh, f16* __restrict__ sl,
    float* __restrict__ rf, float* __restrict__ rs) {
  const int lane = threadIdx.x & 63;
  const int row  = blockIdx.x * 4 + (threadIdx.x >> 6);  // 0..2047
  const float* src = blockIdx.y ? sin_ : fin;
  f16* dh = blockIdx.y ? sh : fh;
  f16* dl = blockIdx.y ? sl : fl;
  float* dr = blockIdx.y ? rs : rf;

  const float4 v = *reinterpret_cast<const float4*>(&src[(size_t)row * DD + lane * 4]);
  const float mean = wrsum(v.x + v.y + v.z + v.w) * (1.0f / DD);
  float c[4] = {v.x - mean, v.y - mean, v.z - mean, v.w - mean};
  const float sq = wrsum(c[0]*c[0] + c[1]*c[1] + c[2]*c[2] + c[3]*c[3]);
  f16x4 hv, lv;
#pragma unroll
  for (int j = 0; j < 4; ++j) {
    f16 h = (f16)c[j];
    hv[j] = h;
    lv[j] = (f16)(c[j] - (float)h);
  }
  *reinterpret_cast<f16x4*>(&dh[(size_t)row * DD + lane * 4]) = hv;
  *reinterpret_cast<f16x4*>(&dl[(size_t)row * DD + lane * 4]) = lv;
  if (lane == 0) dr[row] = 1.0f / fmaxf(sqrtf(sq), 1e-6f);
}

// LUT over corr in [-1,1]: lut[e] = sum_h gelu(exp(c)*w1[h]+b1[h])*w2[h] + b2.
__global__ __launch_bounds__(256) void lut_kernel(
    const float* __restrict__ w1, const float* __restrict__ b1,
    const float* __restrict__ w2, const float* __restrict__ b2,
    float* __restrict__ lut) {
  const int lane = threadIdx.x & 63;
  const int e = blockIdx.x * 4 + (threadIdx.x >> 6);
  if (e > LUTN) return;
  const float corr = -1.0f + (float)e * (2.0f / LUTN);
  const float a = expf(corr);
  float acc = 0.0f;
#pragma unroll
  for (int h = lane; h < 128; h += 64) {
    const float x = fmaf(a, w1[h], b1[h]);
    const float g = 0.5f * x * (1.0f + erff(x * 0.70710678118654752f));
    acc = fmaf(g, w2[h], acc);
  }
  acc = wrsum(acc);
  if (lane == 0) lut[e] = acc + b2[0];
}

// Block 128x64, 4 waves of 64x32 (4x2 frags of 16x16x32_f16), f16 hi/lo split
// (3 MFMAs per frag-pair), BK=64 double-buffered XOR-swizzled LDS.
__global__ __launch_bounds__(256) void gemm_kernel(
    const f16* __restrict__ fh, const f16* __restrict__ fl,
    const f16* __restrict__ sh, const f16* __restrict__ sl,
    const float* __restrict__ rf, const float* __restrict__ rs,
    const float* __restrict__ lut, float* __restrict__ out) {
  __shared__ __align__(16) f16 Ah[2][BM * BK];
  __shared__ __align__(16) f16 Al[2][BM * BK];
  __shared__ __align__(16) f16 Bh[2][BN * BK];
  __shared__ __align__(16) f16 Bl[2][BN * BK];
  __shared__ float lut_s[LUTN + 1];

  const int t = threadIdx.x;
  const int lane = t & 63;
  const int w = t >> 6;
  const int wr = w >> 1, wc = w & 1;   // wave tile: 64x32 at (wr*64, wc*32)
  const int bz = blockIdx.z;
  const int bn0 = blockIdx.x * BN;
  const int bm0 = blockIdx.y * BM;

  const f16* fhb = fh + (size_t)bz * NSEQ * DD;
  const f16* flb = fl + (size_t)bz * NSEQ * DD;
  const f16* shb = sh + (size_t)bz * NSEQ * DD;
  const f16* slb = sl + (size_t)bz * NSEQ * DD;
  const float* rfb = rf + bz * NSEQ;
  const float* rsb = rs + bz * NSEQ;

  for (int i = t; i <= LUTN; i += 256) lut_s[i] = lut[i];

  f16x8 pa_h[4], pa_l[4], pb_h[2], pb_l[2];

  auto load_stage = [&](int s) {
#pragma unroll
    for (int i = 0; i < 4; ++i) {
      const int idx = t + 256 * i;
      const int r = idx >> 3, c = (idx & 7) * 8;
      const size_t g = (size_t)(bm0 + r) * DD + s * BK + c;
      pa_h[i] = *reinterpret_cast<const f16x8*>(&fhb[g]);
      pa_l[i] = *reinterpret_cast<const f16x8*>(&flb[g]);
    }
#pragma unroll
    for (int i = 0; i < 2; ++i) {
      const int idx = t + 256 * i;
      const int r = idx >> 3, c = (idx & 7) * 8;
      const size_t g = (size_t)(bn0 + r) * DD + s * BK + c;
      pb_h[i] = *reinterpret_cast<const f16x8*>(&shb[g]);
      pb_l[i] = *reinterpret_cast<const f16x8*>(&slb[g]);
    }
  };
  auto write_stage = [&](int p) {
#pragma unroll
    for (int i = 0; i < 4; ++i) {
      const int idx = t + 256 * i;
      const int r = idx >> 3, c = (idx & 7) * 8;
      const int o = r * BK + (c ^ ((r & 7) << 3));
      *reinterpret_cast<f16x8*>(&Ah[p][o]) = pa_h[i];
      *reinterpret_cast<f16x8*>(&Al[p][o]) = pa_l[i];
    }
#pragma unroll
    for (int i = 0; i < 2; ++i) {
      const int idx = t + 256 * i;
      const int r = idx >> 3, c = (idx & 7) * 8;
      const int o = r * BK + (c ^ ((r & 7) << 3));
      *reinterpret_cast<f16x8*>(&Bh[p][o]) = pb_h[i];
      *reinterpret_cast<f16x8*>(&Bl[p][o]) = pb_l[i];
    }
  };

  f32x4 acc[4][2] = {};

  load_stage(0);
  write_stage(0);
  __syncthreads();

  for (int s = 0; s < DD / BK; ++s) {
    const int p = s & 1;
    if (s < DD / BK - 1) load_stage(s + 1);   // issue early, HBM/L2 latency hides under MFMA
#pragma unroll
    for (int ks = 0; ks < 2; ++ks) {
      const int kk = ks * 32 + 8 * (lane >> 4);
      f16x8 ah[4], al[4], bh[2], bl[2];
#pragma unroll
      for (int i = 0; i < 4; ++i) {
        const int r = wr * 64 + 16 * i + (lane & 15);
        const int o = r * BK + (kk ^ ((r & 7) << 3));
        ah[i] = *reinterpret_cast<const f16x8*>(&Ah[p][o]);
        al[i] = *reinterpret_cast<const f16x8*>(&Al[p][o]);
      }
#pragma unroll
      for (int j = 0; j < 2; ++j) {
        const int r = wc * 32 + 16 * j + (lane & 15);
        const int o = r * BK + (kk ^ ((r & 7) << 3));
        bh[j] = *reinterpret_cast<const f16x8*>(&Bh[p][o]);
        bl[j] = *reinterpret_cast<const f16x8*>(&Bl[p][o]);
      }
#pragma unroll
      for (int i = 0; i < 4; ++i)
#pragma unroll
        for (int j = 0; j < 2; ++j) {
          acc[i][j] = __builtin_amdgcn_mfma_f32_16x16x32_f16(ah[i], bh[j], acc[i][j], 0, 0, 0);
          acc[i][j] = __builtin_amdgcn_mfma_f32_16x16x32_f16(ah[i], bl[j], acc[i][j], 0, 0, 0);
          acc[i][j] = __builtin_amdgcn_mfma_f32_16x16x32_f16(al[i], bh[j], acc[i][j], 0, 0, 0);
        }
    }
    if (s < DD / BK - 1) write_stage(p ^ 1);  // after compute: vmcnt drain lands late
    __syncthreads();
  }

  // Epilogue: cov -> corr -> clip -> LUT interp -> store.
  float rsv[2];
#pragma unroll
  for (int j = 0; j < 2; ++j) rsv[j] = rsb[bn0 + wc * 32 + 16 * j + (lane & 15)];
#pragma unroll
  for (int i = 0; i < 4; ++i) {
#pragma unroll
    for (int rg = 0; rg < 4; ++rg) {
      const int row = wr * 64 + 16 * i + 4 * (lane >> 4) + rg;
      const float rfv = rfb[bm0 + row];
#pragma unroll
      for (int j = 0; j < 2; ++j) {
        const float cov = acc[i][j][rg] * (1.0f / 16.0f);   // / sqrt(256)
        float corr = cov * rfv * rsv[j];
        corr = fminf(fmaxf(corr, -1.0f), 1.0f);
        const float tf = (corr + 1.0f) * (float)(LUTN / 2);
        int idx = (int)tf;
        idx = idx > (LUTN - 1) ? (LUTN - 1) : idx;
        const float fr = tf - (float)idx;
        const float lo = lut_s[idx], hi = lut_s[idx + 1];
        out[((size_t)bz * NSEQ + bm0 + row) * NSEQ + bn0 + wc * 32 + 16 * j + (lane & 15)]
            = fmaf(fr, hi - lo, lo);
      }
    }
  }
}

extern "C" void kernel_launch(void* const* d_in, const int* in_sizes, int n_in,
                              void* d_out, int out_size, void* d_ws, size_t ws_size,
                              hipStream_t stream) {
  const float* f  = (const float*)d_in[0];
  const float* s  = (const float*)d_in[1];
  const float* w1 = (const float*)d_in[2];
  const float* b1 = (const float*)d_in[3];
  const float* w2 = (const float*)d_in[4];
  const float* b2 = (const float*)d_in[5];
  float* out = (float*)d_out;

  char* ws = (char*)d_ws;
  const size_t NELEM = (size_t)NB * NSEQ * DD;  // 524288
  f16* fh = (f16*)(ws);
  f16* fl = (f16*)(ws + 2 * NELEM);
  f16* sh = (f16*)(ws + 4 * NELEM);
  f16* sl = (f16*)(ws + 6 * NELEM);
  float* rf  = (float*)(ws + 8 * NELEM);
  float* rs  = (float*)(ws + 8 * NELEM + 8192);
  float* lut = (float*)(ws + 8 * NELEM + 16384);

  prep_kernel<<<dim3(512, 2), 256, 0, stream>>>(f, s, fh, fl, sh, sl, rf, rs);
  lut_kernel<<<(LUTN + 1 + 3) / 4, 256, 0, stream>>>(w1, b1, w2, b2, lut);
  gemm_kernel<<<dim3(NSEQ / BN, NSEQ / BM, NB), 256, 0, stream>>>(
      fh, fl, sh, sl, rf, rs, lut, out);
}